// Round 1
// baseline (566.518 us; speedup 1.0000x reference)
//
#include <hip/hip_runtime.h>

namespace {

constexpr int L = 8, H = 1536, W = 1536, HW = H * W, C = 12;
constexpr int TW = 64, TH = 32, HALO = 5;
constexpr int LW = TW + 2 * HALO;   // 74
constexpr int LH = TH + 2 * HALO;   // 42
constexpr int LSTR = 76;            // padded LDS row stride (floats)

// nonzero-tap extents of the 11x11 disc (dist<=5); center weight is 0 but harmless
__device__ constexpr int XLO[11]  = {5, 2, 1, 1, 1, 0, 1, 1, 1, 2, 5};
__device__ constexpr int XHI[11]  = {5, 8, 9, 9, 9,10, 9, 9, 9, 8, 5};
__device__ constexpr int WOFF[11] = {0, 1, 8,17,26,35,46,55,64,73,80};   // 81 total

__global__ __launch_bounds__(256)
void snn_fused(const float* __restrict__ ext,
               const float* __restrict__ spk,
               const float* __restrict__ mem,
               const float* __restrict__ iw,
               const float* __restrict__ lk,
               const int*   __restrict__ refr,
               const int*   __restrict__ csrc,
               const int*   __restrict__ cdst,
               float* __restrict__ out)
{
    __shared__ float tile[LH][LSTR];
    __shared__ float kw[121];

    const int tx  = threadIdx.x;          // 0..63
    const int ty  = threadIdx.y;          // 0..3
    const int tid = ty * 64 + tx;
    const int bx  = blockIdx.x, by = blockIdx.y, l = blockIdx.z;

    if (tid < 121) kw[tid] = lk[tid];

    // ---- stage spike tile (with halo, zero-padded) ----
    const int gx0 = bx * TW - HALO;
    const int gy0 = by * TH - HALO;
    const float* sp_l = spk + l * HW;
    for (int i = tid; i < LH * LW; i += 256) {
        const int r = i / LW, c = i - r * LW;
        const int gy = gy0 + r, gx = gx0 + c;
        float v = 0.f;
        if ((unsigned)gy < (unsigned)H && (unsigned)gx < (unsigned)W)
            v = sp_l[gy * W + gx];
        tile[r][c] = v;
    }
    __syncthreads();

    // ---- cache the 81 used weights in registers (compile-time indices only) ----
    float wreg[81];
    #pragma unroll
    for (int dy = 0; dy < 11; ++dy) {
        #pragma unroll
        for (int dx = XLO[dy]; dx <= XHI[dy]; ++dx)
            wreg[WOFF[dy] + dx - XLO[dy]] = kw[dy * 11 + dx];
    }

    // ---- conv fast path (f32): 8 consecutive output rows per thread ----
    float acc[8] = {0.f,0.f,0.f,0.f,0.f,0.f,0.f,0.f};
    #pragma unroll
    for (int j = 0; j < 18; ++j) {           // LDS row = ty*8 + j
        float d[11];
        #pragma unroll
        for (int dx = 0; dx < 11; ++dx) d[dx] = tile[ty * 8 + j][tx + dx];
        #pragma unroll
        for (int k = 0; k < 8; ++k) {
            const int dy = j - k;
            if (dy < 0 || dy > 10) continue;  // compile-time pruned
            #pragma unroll
            for (int dx = XLO[dy]; dx <= XHI[dy]; ++dx)
                acc[k] += wreg[WOFF[dy] + dx - XLO[dy]] * d[dx];
        }
    }

    // ---- connection topology (uniform) ----
    int cs[C], cd[C];
    #pragma unroll
    for (int c = 0; c < C; ++c) { cs[c] = csrc[c]; cd[c] = cdst[c]; }

    const int ox  = bx * TW + tx;
    const int oy0 = by * TH + ty * 8;

    // ---- axonal fast path (f32) ----
    float axo[8] = {0.f,0.f,0.f,0.f,0.f,0.f,0.f,0.f};
    #pragma unroll
    for (int c = 0; c < C; ++c) {
        if (cd[c] != l) continue;             // uniform branch
        const float* s = spk + cs[c] * HW;
        const float* w = iw  + c     * HW;
        #pragma unroll
        for (int k = 0; k < 8; ++k) {
            const int idx = (oy0 + k) * W + ox;
            axo[k] += s[idx] * w[idx];
        }
    }

    // ---- LIF + threshold; exact f64 recompute for near-threshold pixels ----
    #pragma unroll
    for (int k = 0; k < 8; ++k) {
        const int oy   = oy0 + k;
        const int pidx = oy * W + ox;
        const int gidx = l * HW + pidx;
        const int rf   = refr[gidx];
        float result = 0.f;
        if (rf == 0) {
            const float e = ext[gidx];
            const float m = mem[gidx];
            const float total = e + acc[k] + axo[k];
            const float v = 0.9f * m + total;
            if (fabsf(v) < 1e-3f) {
                // rare exact path: full 121 taps in f64 (zero taps add exact 0)
                double conv = 0.0;
                for (int dy = 0; dy < 11; ++dy)
                    for (int dx = 0; dx < 11; ++dx)
                        conv += (double)kw[dy * 11 + dx] *
                                (double)tile[ty * 8 + k + dy][tx + dx];
                double ax = 0.0;
                #pragma unroll
                for (int c = 0; c < C; ++c)
                    if (cd[c] == l)
                        ax += (double)spk[cs[c] * HW + pidx] *
                              (double)iw[c * HW + pidx];
                const double tot = ((double)e + conv) + ax;
                const double vd  = 0.9 * (double)m + tot;
                result = (vd > 0.0) ? 1.f : 0.f;
            } else {
                result = (v > 0.f) ? 1.f : 0.f;
            }
        }
        out[gidx] = result;
    }
}

} // namespace

extern "C" void kernel_launch(void* const* d_in, const int* in_sizes, int n_in,
                              void* d_out, int out_size, void* d_ws, size_t ws_size,
                              hipStream_t stream) {
    const float* ext  = (const float*)d_in[0];
    const float* spk  = (const float*)d_in[1];
    const float* mem  = (const float*)d_in[2];
    const float* iw   = (const float*)d_in[3];
    const float* lk   = (const float*)d_in[4];
    const int*   refr = (const int*)  d_in[5];
    const int*   csrc = (const int*)  d_in[6];
    const int*   cdst = (const int*)  d_in[7];
    float* o = (float*)d_out;

    dim3 grid(W / TW, H / TH, L);   // (24, 48, 8)
    dim3 block(64, 4, 1);
    hipLaunchKernelGGL(snn_fused, grid, block, 0, stream,
                       ext, spk, mem, iw, lk, refr, csrc, cdst, o);
}